// Round 1
// baseline (380.500 us; speedup 1.0000x reference)
//
#include <hip/hip_runtime.h>

#define BB   128
#define DD   128
#define OUTN 100000
#define KP1  4097     // K+1
#define TEMP 0.07f

// ---------------------------------------------------------------------------
// Kernel A: unscaled scores s = exp(dot(mem[idx], z1)/T) for both memories.
// One wave (64 lanes) per (b,k) pair; lane l loads float2 at row+2l (512B
// coalesced per wave). Butterfly shuffle reduce, expf on all lanes, lane 0
// writes. Block-partial sums -> one atomicAdd per block per memory.
// ---------------------------------------------------------------------------
__global__ __launch_bounds__(256) void scores_kernel(
    const float* __restrict__ z1,
    const float* __restrict__ mem2,
    const float* __restrict__ mem3,
    const int*   __restrict__ y,
    const int*   __restrict__ idx,
    float* __restrict__ out,     // s2 at [0, B*KP1), s3 at [B*KP1, 2*B*KP1)
    float* __restrict__ sums)    // sums[0]=sum(s2), sums[1]=sum(s3)
{
    __shared__ float z1s[DD];
    __shared__ float part2[4], part3[4];

    const int b    = blockIdx.y;
    const int tid  = threadIdx.x;
    const int wave = tid >> 6;
    const int lane = tid & 63;

    if (tid < DD) z1s[tid] = z1[b * DD + tid];
    __syncthreads();

    const float za = z1s[2 * lane];
    const float zb = z1s[2 * lane + 1];
    const int   yb = y[b];

    float lsum2 = 0.f, lsum3 = 0.f;

    for (int k = blockIdx.x * 4 + wave; k < KP1; k += gridDim.x * 4) {
        const int j = (k == 0) ? yb : idx[b * KP1 + k];
        const float2 r2 = *(const float2*)(mem2 + (size_t)j * DD + 2 * lane);
        const float2 r3 = *(const float2*)(mem3 + (size_t)j * DD + 2 * lane);
        float d2 = r2.x * za + r2.y * zb;
        float d3 = r3.x * za + r3.y * zb;
        #pragma unroll
        for (int off = 32; off > 0; off >>= 1) {
            d2 += __shfl_xor(d2, off);
            d3 += __shfl_xor(d3, off);
        }
        const float s2 = expf(d2 / TEMP);
        const float s3 = expf(d3 / TEMP);
        if (lane == 0) {
            out[b * KP1 + k]            = s2;
            out[BB * KP1 + b * KP1 + k] = s3;
            lsum2 += s2;
            lsum3 += s3;
        }
    }

    if (lane == 0) { part2[wave] = lsum2; part3[wave] = lsum3; }
    __syncthreads();
    if (tid == 0) {
        float t2 = part2[0] + part2[1] + part2[2] + part2[3];
        float t3 = part3[0] + part3[1] + part3[2] + part3[3];
        atomicAdd(&sums[0], t2);
        atomicAdd(&sums[1], t3);
    }
}

// ---------------------------------------------------------------------------
// Kernel B: I = s / Z, Z = (sum / (B*KP1)) * OUTN  =>  I = s * (B*KP1)/(OUTN*sum)
// ---------------------------------------------------------------------------
__global__ __launch_bounds__(256) void scale_kernel(
    float* __restrict__ out, const float* __restrict__ sums)
{
    const int i = blockIdx.x * blockDim.x + threadIdx.x;
    if (i >= 2 * BB * KP1) return;
    const float sum   = (i < BB * KP1) ? sums[0] : sums[1];
    const float scale = (float)((double)(BB * KP1) / ((double)OUTN * (double)sum));
    out[i] *= scale;
}

// ---------------------------------------------------------------------------
// Kernel C: copy both memories to output regions (float4, grid-stride).
// ---------------------------------------------------------------------------
__global__ __launch_bounds__(256) void copy_kernel(
    const float4* __restrict__ m2,
    const float4* __restrict__ m3,
    float4* __restrict__ dst)     // dst = out + 2*B*KP1 (in floats), /4 in float4
{
    const int n1 = OUTN * DD / 4;           // 3,200,000
    const int stride = gridDim.x * blockDim.x;
    for (int i = blockIdx.x * blockDim.x + threadIdx.x; i < 2 * n1; i += stride) {
        dst[i] = (i < n1) ? m2[i] : m3[i - n1];
    }
}

// ---------------------------------------------------------------------------
// Kernel D: row update.  pos = -mem[y[b]] + 2*z[b]  (momentum = -1.0),
// L2-normalize, scatter to output rows. Last-write-wins on duplicate y.
// One wave per b.
// ---------------------------------------------------------------------------
__global__ __launch_bounds__(64) void update_kernel(
    const float* __restrict__ z2,
    const float* __restrict__ z3,
    const float* __restrict__ mem2,
    const float* __restrict__ mem3,
    const int*   __restrict__ y,
    float* __restrict__ out2,    // out + 2*B*KP1
    float* __restrict__ out3)    // out + 2*B*KP1 + OUTN*DD
{
    const int b    = blockIdx.x;
    const int lane = threadIdx.x;   // 0..63
    const int yb   = y[b];

    // last-write-wins: if any later b' writes the same row, skip this one
    for (int bp = b + 1; bp < BB; ++bp)
        if (y[bp] == yb) return;

    const float2 m2 = *(const float2*)(mem2 + (size_t)yb * DD + 2 * lane);
    const float2 m3 = *(const float2*)(mem3 + (size_t)yb * DD + 2 * lane);
    const float2 a2 = *(const float2*)(z2 + b * DD + 2 * lane);
    const float2 a3 = *(const float2*)(z3 + b * DD + 2 * lane);

    float2 p2, p3;
    p2.x = 2.f * a2.x - m2.x;  p2.y = 2.f * a2.y - m2.y;
    p3.x = 2.f * a3.x - m3.x;  p3.y = 2.f * a3.y - m3.y;

    float ss2 = p2.x * p2.x + p2.y * p2.y;
    float ss3 = p3.x * p3.x + p3.y * p3.y;
    #pragma unroll
    for (int off = 32; off > 0; off >>= 1) {
        ss2 += __shfl_xor(ss2, off);
        ss3 += __shfl_xor(ss3, off);
    }
    const float inv2 = 1.f / sqrtf(ss2);
    const float inv3 = 1.f / sqrtf(ss3);

    float2 w2, w3;
    w2.x = p2.x * inv2;  w2.y = p2.y * inv2;
    w3.x = p3.x * inv3;  w3.y = p3.y * inv3;
    *(float2*)(out2 + (size_t)yb * DD + 2 * lane) = w2;
    *(float2*)(out3 + (size_t)yb * DD + 2 * lane) = w3;
}

// ---------------------------------------------------------------------------
extern "C" void kernel_launch(void* const* d_in, const int* in_sizes, int n_in,
                              void* d_out, int out_size, void* d_ws, size_t ws_size,
                              hipStream_t stream)
{
    const float* z1   = (const float*)d_in[0];
    const float* z2   = (const float*)d_in[1];
    const float* z3   = (const float*)d_in[2];
    const float* mem2 = (const float*)d_in[3];
    const float* mem3 = (const float*)d_in[4];
    const int*   y    = (const int*)d_in[5];
    const int*   idx  = (const int*)d_in[6];
    float*       out  = (float*)d_out;
    float*       sums = (float*)d_ws;

    // zero the two accumulators (ws is re-poisoned 0xAA before every call)
    hipMemsetAsync(d_ws, 0, 2 * sizeof(float), stream);

    // A: scores (unscaled) + global sums
    dim3 gA(32, BB);
    scores_kernel<<<gA, 256, 0, stream>>>(z1, mem2, mem3, y, idx, out, sums);

    // B: normalize scores by Z
    const int nScores = 2 * BB * KP1;
    scale_kernel<<<(nScores + 255) / 256, 256, 0, stream>>>(out, sums);

    // C: copy memories to output
    copy_kernel<<<2048, 256, 0, stream>>>((const float4*)mem2, (const float4*)mem3,
                                          (float4*)(out + 2 * BB * KP1));

    // D: updated rows (after copy, same stream => ordered)
    update_kernel<<<BB, 64, 0, stream>>>(z2, z3, mem2, mem3, y,
                                         out + 2 * BB * KP1,
                                         out + 2 * BB * KP1 + OUTN * DD);
}

// Round 3
// 308.398 us; speedup vs baseline: 1.2338x; 1.2338x over previous
//
#include <hip/hip_runtime.h>

#define BB   128
#define DD   128
#define OUTN 100000
#define KP1  4097     // K+1
#define TEMP 0.07f

// ---------------------------------------------------------------------------
// Kernel A: unscaled scores s = exp(dot(mem[idx], z1)/T) for both memories.
// Thread-per-(b,k): each thread reads two 512B rows with 64 independent
// float4 loads (deep MLP in flight), dot accumulated in-register.
// z1[b] is wave-uniform -> scalar loads. Block partial sums go to 64
// bucket slots to avoid atomic contention.
// ---------------------------------------------------------------------------
__global__ __launch_bounds__(256) void scores_kernel(
    const float* __restrict__ z1,
    const float* __restrict__ mem2,
    const float* __restrict__ mem3,
    const int*   __restrict__ y,
    const int*   __restrict__ idx,
    float* __restrict__ out,     // s2 at [0, B*KP1), s3 at [B*KP1, 2*B*KP1)
    float* __restrict__ part)    // part[0..63]=sum2 buckets, part[64..127]=sum3
{
    const int b     = blockIdx.y;
    const int k     = blockIdx.x * blockDim.x + threadIdx.x;
    const bool valid = (k < KP1);
    const int yb    = y[b];

    int j = 0;
    if (valid) j = (k == 0) ? yb : idx[b * KP1 + k];

    const float4* __restrict__ r2 = (const float4*)(mem2 + (size_t)j * DD);
    const float4* __restrict__ r3 = (const float4*)(mem3 + (size_t)j * DD);
    const float4* __restrict__ zz = (const float4*)(z1 + (size_t)b * DD);

    float d2 = 0.f, d3 = 0.f;
    #pragma unroll 8
    for (int c = 0; c < DD / 4; ++c) {
        const float4 zv = zz[c];      // uniform -> s_load
        const float4 a2 = r2[c];
        const float4 a3 = r3[c];
        d2 += a2.x * zv.x + a2.y * zv.y + a2.z * zv.z + a2.w * zv.w;
        d3 += a3.x * zv.x + a3.y * zv.y + a3.z * zv.z + a3.w * zv.w;
    }

    float s2 = 0.f, s3 = 0.f;
    if (valid) {
        s2 = expf(d2 * (1.0f / TEMP));
        s3 = expf(d3 * (1.0f / TEMP));
        out[b * KP1 + k]            = s2;
        out[BB * KP1 + b * KP1 + k] = s3;
    }

    // wave reduce (once per 64 scores)
    #pragma unroll
    for (int off = 32; off > 0; off >>= 1) {
        s2 += __shfl_xor(s2, off);
        s3 += __shfl_xor(s3, off);
    }
    __shared__ float w2[4], w3[4];
    const int wave = threadIdx.x >> 6;
    const int lane = threadIdx.x & 63;
    if (lane == 0) { w2[wave] = s2; w3[wave] = s3; }
    __syncthreads();
    if (threadIdx.x == 0) {
        const float t2 = w2[0] + w2[1] + w2[2] + w2[3];
        const float t3 = w3[0] + w3[1] + w3[2] + w3[3];
        const int slot = (blockIdx.y * gridDim.x + blockIdx.x) & 63;
        atomicAdd(&part[slot],      t2);
        atomicAdd(&part[64 + slot], t3);
    }
}

// ---------------------------------------------------------------------------
// Kernel B: I = s / Z, Z = (sum/(B*KP1))*OUTN  =>  I = s * (B*KP1)/(OUTN*sum)
// Each block redundantly folds the 64 buckets (cheap, uniform).
// ---------------------------------------------------------------------------
__global__ __launch_bounds__(256) void scale_kernel(
    float* __restrict__ out, const float* __restrict__ part)
{
    __shared__ float sc[2];
    if (threadIdx.x == 0) {
        float t2 = 0.f, t3 = 0.f;
        for (int i = 0; i < 64; ++i) { t2 += part[i]; t3 += part[64 + i]; }
        sc[0] = (float)((double)(BB * KP1) / ((double)OUTN * (double)t2));
        sc[1] = (float)((double)(BB * KP1) / ((double)OUTN * (double)t3));
    }
    __syncthreads();
    const int i = blockIdx.x * blockDim.x + threadIdx.x;
    if (i >= 2 * BB * KP1) return;
    out[i] *= sc[(i < BB * KP1) ? 0 : 1];
}

// ---------------------------------------------------------------------------
// Kernel C: copy both memories to output regions (float4, grid-stride).
// ---------------------------------------------------------------------------
__global__ __launch_bounds__(256) void copy_kernel(
    const float4* __restrict__ m2,
    const float4* __restrict__ m3,
    float4* __restrict__ dst)
{
    const int n1 = OUTN * DD / 4;           // 3,200,000
    const int stride = gridDim.x * blockDim.x;
    for (int i = blockIdx.x * blockDim.x + threadIdx.x; i < 2 * n1; i += stride) {
        dst[i] = (i < n1) ? m2[i] : m3[i - n1];
    }
}

// ---------------------------------------------------------------------------
// Kernel D: row update.  pos = 2*z[b] - mem[y[b]]  (momentum = -1.0),
// L2-normalize, scatter. Last-write-wins on duplicate y. One wave per b.
// ---------------------------------------------------------------------------
__global__ __launch_bounds__(64) void update_kernel(
    const float* __restrict__ z2,
    const float* __restrict__ z3,
    const float* __restrict__ mem2,
    const float* __restrict__ mem3,
    const int*   __restrict__ y,
    float* __restrict__ out2,
    float* __restrict__ out3)
{
    const int b    = blockIdx.x;
    const int lane = threadIdx.x;   // 0..63
    const int yb   = y[b];

    for (int bp = b + 1; bp < BB; ++bp)
        if (y[bp] == yb) return;    // a later b' overwrites this row

    const float2 m2 = *(const float2*)(mem2 + (size_t)yb * DD + 2 * lane);
    const float2 m3 = *(const float2*)(mem3 + (size_t)yb * DD + 2 * lane);
    const float2 a2 = *(const float2*)(z2 + b * DD + 2 * lane);
    const float2 a3 = *(const float2*)(z3 + b * DD + 2 * lane);

    float2 p2, p3;
    p2.x = 2.f * a2.x - m2.x;  p2.y = 2.f * a2.y - m2.y;
    p3.x = 2.f * a3.x - m3.x;  p3.y = 2.f * a3.y - m3.y;

    float ss2 = p2.x * p2.x + p2.y * p2.y;
    float ss3 = p3.x * p3.x + p3.y * p3.y;
    #pragma unroll
    for (int off = 32; off > 0; off >>= 1) {
        ss2 += __shfl_xor(ss2, off);
        ss3 += __shfl_xor(ss3, off);
    }
    const float inv2 = 1.f / sqrtf(ss2);
    const float inv3 = 1.f / sqrtf(ss3);

    float2 w2, w3;
    w2.x = p2.x * inv2;  w2.y = p2.y * inv2;
    w3.x = p3.x * inv3;  w3.y = p3.y * inv3;
    *(float2*)(out2 + (size_t)yb * DD + 2 * lane) = w2;
    *(float2*)(out3 + (size_t)yb * DD + 2 * lane) = w3;
}

// ---------------------------------------------------------------------------
extern "C" void kernel_launch(void* const* d_in, const int* in_sizes, int n_in,
                              void* d_out, int out_size, void* d_ws, size_t ws_size,
                              hipStream_t stream)
{
    const float* z1   = (const float*)d_in[0];
    const float* z2   = (const float*)d_in[1];
    const float* z3   = (const float*)d_in[2];
    const float* mem2 = (const float*)d_in[3];
    const float* mem3 = (const float*)d_in[4];
    const int*   y    = (const int*)d_in[5];
    const int*   idx  = (const int*)d_in[6];
    float*       out  = (float*)d_out;
    float*       part = (float*)d_ws;

    hipMemsetAsync(d_ws, 0, 128 * sizeof(float), stream);

    // A: scores (unscaled) + bucketed partial sums
    dim3 gA((KP1 + 255) / 256, BB);   // 17 x 128 blocks
    scores_kernel<<<gA, 256, 0, stream>>>(z1, mem2, mem3, y, idx, out, part);

    // B: normalize scores by Z
    const int nScores = 2 * BB * KP1;
    scale_kernel<<<(nScores + 255) / 256, 256, 0, stream>>>(out, part);

    // C: copy memories to output
    copy_kernel<<<2048, 256, 0, stream>>>((const float4*)mem2, (const float4*)mem3,
                                          (float4*)(out + 2 * BB * KP1));

    // D: updated rows (same stream => ordered after copy)
    update_kernel<<<BB, 64, 0, stream>>>(z2, z3, mem2, mem3, y,
                                         out + 2 * BB * KP1,
                                         out + 2 * BB * KP1 + OUTN * DD);
}